// Round 15
// baseline (255.967 us; speedup 1.0000x reference)
//
#include <hip/hip_runtime.h>
#include <hip/hip_fp16.h>

// Shapes (fixed by the reference setup_inputs)
#define NB 2
#define NH 16
#define NS 2048
#define ND 64

typedef __attribute__((ext_vector_type(8))) _Float16 half8;
typedef __attribute__((ext_vector_type(4))) _Float16 half4;
typedef __attribute__((ext_vector_type(4))) float float4v;

static constexpr int NE = NB * NH * NS * ND;     // 4,194,304 elems per tensor
static constexpr int TPB = 512;                  // 8 waves

// LDS-only workgroup barrier (R14-verified, -45us vs __syncthreads):
// syncs LDS writes across waves WITHOUT the vmcnt(0) drain, so nt/global
// stores stay in flight across the barrier.
__device__ __forceinline__ void wg_barrier_lds() {
    asm volatile("s_waitcnt lgkmcnt(0)" ::: "memory");
    __builtin_amdgcn_s_barrier();
    __builtin_amdgcn_sched_barrier(0);
}

// ---------------------------------------------------------------------------
// Fused prep kernel: three independent streams in ONE launch so their
// memory traffic overlaps (separate launches serialize at kernel bounds).
//   blocks [0, 8192):            RoPE(q)->qr, RoPE(k)->kr6 (tiled)
//   blocks [8192, 8192+16384):   V -> v4 (tiled fp16)
//   blocks [24576, 24576+32768): mask -> bit-packed mp
// kr6 (per bh): [kt][oct=d/8][key%16][d%8] -> QK^T B-frag load is 1024B contig.
// v4  (per bh): [kt][dblk=d/16][kq][d%16][key%4] -> PV A-frag load 512B contig.
// ---------------------------------------------------------------------------
static constexpr int ROPE_BLKS = (NE / 2) / 256;          // 8192
static constexpr int VT_BLKS   = NE / 256;                // 16384
static constexpr int MP_BLKS   = (NB * NS * NS) / 256;    // 32768

__global__ void prep_kernel(const float* __restrict__ q,
                            const float* __restrict__ k,
                            const float* __restrict__ v,
                            const int* __restrict__ mask,
                            _Float16* __restrict__ qr,
                            _Float16* __restrict__ kr6,
                            _Float16* __restrict__ v4,
                            unsigned int* __restrict__ mp) {
    int blk = blockIdx.x;
    if (blk < ROPE_BLKS) {
        int idx = blk * 256 + threadIdx.x;          // over NE/2
        int i   = idx & 31;        // freq index (d pair = 2i, 2i+1)
        int row = idx >> 5;        // (b*NH + h)*NS + s
        int s   = row & (NS - 1);
        int bh  = row >> 11;

        float inv_freq = expf((float)i * -0.2878231366242710f);  // 10000^(-i/32)
        float ang = (float)s * inv_freq;
        float sn, cs;
        sincosf(ang, &sn, &cs);

        size_t base = (size_t)row * ND + 2 * i;
        float q0 = q[base], q1 = q[base + 1];
        float k0 = k[base], k1 = k[base + 1];
        qr[base]     = (_Float16)(q0 * cs - q1 * sn);
        qr[base + 1] = (_Float16)(q1 * cs + q0 * sn);

        int oct = i >> 2;
        int j0  = (2 * i) & 7;
        size_t t6 = ((size_t)(bh * 128 + (s >> 4)) * 8 + oct) * 128 + (s & 15) * 8 + j0;
        kr6[t6]     = (_Float16)(k0 * cs - k1 * sn);
        kr6[t6 + 1] = (_Float16)(k1 * cs + k0 * sn);
    } else if (blk < ROPE_BLKS + VT_BLKS) {
        int idx = (blk - ROPE_BLKS) * 256 + threadIdx.x;   // linear v4 index
        int j    = idx & 3;            // key%4
        int lm   = (idx >> 2) & 15;    // d%16
        int kq   = (idx >> 6) & 3;     // (key%16)/4
        int dblk = (idx >> 8) & 3;
        int kt   = (idx >> 10) & 127;
        int bh   = idx >> 17;
        int key  = kt * 16 + kq * 4 + j;
        int d    = dblk * 16 + lm;
        v4[idx] = (_Float16)v[((size_t)bh * NS + key) * ND + d];
    } else {
        size_t idx = (size_t)(blk - ROPE_BLKS - VT_BLKS) * 256 + threadIdx.x;
        unsigned long long bal = __ballot(mask[idx] != 0);
        int l = threadIdx.x & 63;
        if (l == 0)       mp[idx >> 5] = (unsigned int)bal;
        else if (l == 32) mp[idx >> 5] = (unsigned int)(bal >> 32);
    }
}

// ---------------------------------------------------------------------------
// Attention kernel (R14 structure; R15 delta: score stores are PLAIN, not
// nt — A/B on the write path. R5's nt win was under heavy K-reread L2
// thrash; with tiled kr6/v4 the K/V traffic is small, so routing the
// 537 MB score stream through L2's write-combining may sustain higher BW
// (fill kernel: 6.6 TB/s through L2 vs our 2.9 effective with nt).
// DETERMINISM RULES kept: no LDS atomics/init; unique-owner LDS writes
// before barrier; fixed-order final sums.
// ---------------------------------------------------------------------------
__global__ __launch_bounds__(TPB, 4)
void attn_reg_kernel(const _Float16* __restrict__ qr,
                     const _Float16* __restrict__ kr6,
                     const _Float16* __restrict__ v4,
                     const unsigned int* __restrict__ mp,
                     float* __restrict__ out,
                     float* __restrict__ score) {
    __shared__ unsigned int maskb[16 * 64];       // 4 KB
    __shared__ float        sums8[8][16];         // 512 B, per-wave slots
    __shared__ float        outb[8 * 16 * 64];    // 32 KB, per-wave slices

    // XCD-aware bijective swizzle: 4096 WGs -> contiguous 512 per XCD
    int wgid = (blockIdx.x & 7) * 512 + (blockIdx.x >> 3);
    int qt = wgid & 127;
    int bh = wgid >> 7;
    int b  = bh >> 4;
    int q0 = qt * 16;

    int tid = threadIdx.x;
    int w   = tid >> 6;
    int l   = tid & 63;
    int lm  = l & 15;
    int lp  = l >> 4;

    {
        const unsigned int* mrow = mp + ((size_t)b * NS + q0) * 64;
        for (int i = tid; i < 16 * 64; i += TPB) maskb[i] = mrow[i];
    }

    // Q B-fragment (col n = q = lm, k-slice d = lp*8+[0..7] (+32))
    const _Float16* qrow = qr + ((size_t)bh * NS + q0 + lm) * ND;
    half8 a0 = *(const half8*)(qrow + lp * 8);
    half8 a1 = *(const half8*)(qrow + 32 + lp * 8);
    // kr6 base for this bh; wave w covers key-tiles [w*16, w*16+16)
    const _Float16* k6 = kr6 + (size_t)bh * 128 * 1024;
    wg_barrier_lds();                      // maskb visible

    // ---- phase 1: S^T = K·Q^T -> masked exp -> packed regs + lane row-sum ----
    half4 earr[16];
    float ps = 0.0f;
#pragma unroll
    for (int t = 0; t < 16; ++t) {
        int kt = w * 16 + t;
        const _Float16* kp = k6 + (size_t)kt * 1024 + l * 8;
        half8 b0 = *(const half8*)(kp);          // 1024B contiguous wave-load
        half8 b1 = *(const half8*)(kp + 512);
        float4v acc = {0.f, 0.f, 0.f, 0.f};
        acc = __builtin_amdgcn_mfma_f32_16x16x32_f16(b0, a0, acc, 0, 0, 0);  // A=K rows
        acc = __builtin_amdgcn_mfma_f32_16x16x32_f16(b1, a1, acc, 0, 0, 0);  // B=Q rows
        // acc[r]: key = kt*16 + lp*4 + r, q = q0 + lm
        int keyb = kt * 16 + lp * 4;
        unsigned int mw = maskb[lm * 64 + (keyb >> 5)];
        int bit0 = keyb & 31;
        half4 ep;
#pragma unroll
        for (int r = 0; r < 4; ++r) {
            float ev = ((mw >> (bit0 + r)) & 1u) ? __expf(acc[r] * 0.125f) : 0.0f;
            ps += ev;
            ep[r] = (_Float16)ev;
        }
        earr[t] = ep;
    }
    ps += __shfl_xor(ps, 16);
    ps += __shfl_xor(ps, 32);
    if (lp == 0) sums8[w][lm] = ps;        // plain store, unique slot
    wg_barrier_lds();                       // sums8 visible (stores NOT drained)

    // ---- phase 2: interleaved {score store | PV MFMA} per key-subtile ----
    {
        float s = 0.0f;
#pragma unroll
        for (int ww = 0; ww < 8; ++ww) s += sums8[ww][lm];   // fixed order
        float iv = (s > 0.0f) ? (1.0f / s) : 0.0f;
        float* srow = score + ((size_t)bh * NS + q0 + lm) * NS + w * 256 + lp * 4;

        float4v ac0 = {0.f, 0.f, 0.f, 0.f};
        float4v ac1 = {0.f, 0.f, 0.f, 0.f};
        float4v ac2 = {0.f, 0.f, 0.f, 0.f};
        float4v ac3 = {0.f, 0.f, 0.f, 0.f};
        const _Float16* vb = v4 + (size_t)bh * 128 * 1024 + l * 4;
#pragma unroll
        for (int st = 0; st < 16; ++st) {
            // score store for this key-subtile (PLAIN: ride L2 write-combining)
            half4 e = earr[st];
            float4v f;
            f[0] = (float)e[0] * iv;
            f[1] = (float)e[1] * iv;
            f[2] = (float)e[2] * iv;
            f[3] = (float)e[3] * iv;
            *(float4v*)(srow + st * 16) = f;

            // PV for this key-subtile
            int kt = w * 16 + st;
            const _Float16* vp = vb + (size_t)kt * 1024;
            half4 af0 = *(const half4*)(vp);         // 512B contiguous wave-loads
            half4 af1 = *(const half4*)(vp + 256);
            half4 af2 = *(const half4*)(vp + 512);
            half4 af3 = *(const half4*)(vp + 768);
            __builtin_amdgcn_s_setprio(1);
            ac0 = __builtin_amdgcn_mfma_f32_16x16x16f16(af0, e, ac0, 0, 0, 0);
            ac1 = __builtin_amdgcn_mfma_f32_16x16x16f16(af1, e, ac1, 0, 0, 0);
            ac2 = __builtin_amdgcn_mfma_f32_16x16x16f16(af2, e, ac2, 0, 0, 0);
            ac3 = __builtin_amdgcn_mfma_f32_16x16x16f16(af3, e, ac3, 0, 0, 0);
            __builtin_amdgcn_s_setprio(0);
        }
        // C-frag: q = lm (cols), d_local = lp*4 + reg; per-wave slice, plain stores
        float* ow = outb + w * 1024 + lm * 64 + lp * 4;
#pragma unroll
        for (int r = 0; r < 4; ++r) {
            ow[ 0 + r] = ac0[r];
            ow[16 + r] = ac1[r];
            ow[32 + r] = ac2[r];
            ow[48 + r] = ac3[r];
        }
    }
    wg_barrier_lds();   // outb visible (score stores still in flight)

    // ---- phase 3: out = (sum of 8 wave slices) * invs (nt) ----
    {
        float* orow = out + ((size_t)bh * NS + q0) * ND;
        for (int i = tid; i < 16 * 64; i += TPB) {
            int r = i >> 6;
            float s = 0.0f;
#pragma unroll
            for (int ww = 0; ww < 8; ++ww) s += sums8[ww][r];  // fixed order
            float iv = (s > 0.0f) ? (1.0f / s) : 0.0f;
            float acc = 0.0f;
#pragma unroll
            for (int ww = 0; ww < 8; ++ww) acc += outb[ww * 1024 + i];
            __builtin_nontemporal_store(acc * iv, &orow[i]);
        }
    }
}

// ---------------------------------------------------------------------------
extern "C" void kernel_launch(void* const* d_in, const int* in_sizes, int n_in,
                              void* d_out, int out_size, void* d_ws, size_t ws_size,
                              hipStream_t stream) {
    const float* q    = (const float*)d_in[0];
    const float* k    = (const float*)d_in[1];
    const float* v    = (const float*)d_in[2];
    const int*   mask = (const int*)d_in[3];

    float* out   = (float*)d_out;            // [B,H,S,D]
    float* score = out + (size_t)NE;         // [B,H,S,S]

    _Float16* qrw = (_Float16*)d_ws;
    _Float16* kr6 = qrw + NE;
    _Float16* v4w = kr6 + NE;
    unsigned int* mp = (unsigned int*)(v4w + NE);   // NB*NS*NS/32 words = 1 MB

    prep_kernel<<<dim3(ROPE_BLKS + VT_BLKS + MP_BLKS), dim3(256), 0, stream>>>(
        q, k, v, mask, qrw, kr6, v4w, mp);
    attn_reg_kernel<<<dim3(NB * NH * (NS / 16)), dim3(TPB), 0, stream>>>(
        qrw, kr6, v4w, mp, out, score);
}

// Round 16
// 208.875 us; speedup vs baseline: 1.2255x; 1.2255x over previous
//
#include <hip/hip_runtime.h>
#include <hip/hip_fp16.h>

// Shapes (fixed by the reference setup_inputs)
#define NB 2
#define NH 16
#define NS 2048
#define ND 64

typedef __attribute__((ext_vector_type(8))) _Float16 half8;
typedef __attribute__((ext_vector_type(4))) _Float16 half4;
typedef __attribute__((ext_vector_type(4))) float float4v;

static constexpr int NE = NB * NH * NS * ND;     // 4,194,304 elems per tensor
static constexpr int TPB = 512;                  // 8 waves

// LDS-only workgroup barrier (R14-verified, -45us vs __syncthreads):
// syncs LDS writes across waves WITHOUT the vmcnt(0) drain, so nt/global
// stores stay in flight across the barrier.
__device__ __forceinline__ void wg_barrier_lds() {
    asm volatile("s_waitcnt lgkmcnt(0)" ::: "memory");
    __builtin_amdgcn_s_barrier();
    __builtin_amdgcn_sched_barrier(0);
}

// ---------------------------------------------------------------------------
// Fused prep kernel (kept from R15): three independent streams in ONE launch.
//   blocks [0, 8192):            RoPE(q)->qr, RoPE(k)->kr6 (tiled)
//   blocks [8192, 8192+16384):   V -> v4 (tiled fp16)
//   blocks [24576, 24576+32768): mask -> bit-packed mp
// kr6 (per bh): [kt][oct=d/8][key%16][d%8] -> QK^T B-frag load is 1024B contig.
// v4  (per bh): [kt][dblk=d/16][kq][d%16][key%4] -> PV A-frag load 512B contig.
// ---------------------------------------------------------------------------
static constexpr int ROPE_BLKS = (NE / 2) / 256;          // 8192
static constexpr int VT_BLKS   = NE / 256;                // 16384
static constexpr int MP_BLKS   = (NB * NS * NS) / 256;    // 32768

__global__ void prep_kernel(const float* __restrict__ q,
                            const float* __restrict__ k,
                            const float* __restrict__ v,
                            const int* __restrict__ mask,
                            _Float16* __restrict__ qr,
                            _Float16* __restrict__ kr6,
                            _Float16* __restrict__ v4,
                            unsigned int* __restrict__ mp) {
    int blk = blockIdx.x;
    if (blk < ROPE_BLKS) {
        int idx = blk * 256 + threadIdx.x;          // over NE/2
        int i   = idx & 31;        // freq index (d pair = 2i, 2i+1)
        int row = idx >> 5;        // (b*NH + h)*NS + s
        int s   = row & (NS - 1);
        int bh  = row >> 11;

        float inv_freq = expf((float)i * -0.2878231366242710f);  // 10000^(-i/32)
        float ang = (float)s * inv_freq;
        float sn, cs;
        sincosf(ang, &sn, &cs);

        size_t base = (size_t)row * ND + 2 * i;
        float q0 = q[base], q1 = q[base + 1];
        float k0 = k[base], k1 = k[base + 1];
        qr[base]     = (_Float16)(q0 * cs - q1 * sn);
        qr[base + 1] = (_Float16)(q1 * cs + q0 * sn);

        int oct = i >> 2;
        int j0  = (2 * i) & 7;
        size_t t6 = ((size_t)(bh * 128 + (s >> 4)) * 8 + oct) * 128 + (s & 15) * 8 + j0;
        kr6[t6]     = (_Float16)(k0 * cs - k1 * sn);
        kr6[t6 + 1] = (_Float16)(k1 * cs + k0 * sn);
    } else if (blk < ROPE_BLKS + VT_BLKS) {
        int idx = (blk - ROPE_BLKS) * 256 + threadIdx.x;   // linear v4 index
        int j    = idx & 3;            // key%4
        int lm   = (idx >> 2) & 15;    // d%16
        int kq   = (idx >> 6) & 3;     // (key%16)/4
        int dblk = (idx >> 8) & 3;
        int kt   = (idx >> 10) & 127;
        int bh   = idx >> 17;
        int key  = kt * 16 + kq * 4 + j;
        int d    = dblk * 16 + lm;
        v4[idx] = (_Float16)v[((size_t)bh * NS + key) * ND + d];
    } else {
        size_t idx = (size_t)(blk - ROPE_BLKS - VT_BLKS) * 256 + threadIdx.x;
        unsigned long long bal = __ballot(mask[idx] != 0);
        int l = threadIdx.x & 63;
        if (l == 0)       mp[idx >> 5] = (unsigned int)bal;
        else if (l == 32) mp[idx >> 5] = (unsigned int)(bal >> 32);
    }
}

// ---------------------------------------------------------------------------
// Attention kernel — byte-identical to R14's (212.3 us): nt score stores
// RESTORED (R15's plain-store A/B cost +44 us: the 537 MB plain stream
// evicts each XCD's ~2 MB kr6/v4 L2 working set; nt preserves operand
// residency). LDS-only barriers, interleaved score/PV, setprio.
// DETERMINISM RULES kept: no LDS atomics/init; unique-owner LDS writes
// before barrier; fixed-order final sums.
// ---------------------------------------------------------------------------
__global__ __launch_bounds__(TPB, 4)
void attn_reg_kernel(const _Float16* __restrict__ qr,
                     const _Float16* __restrict__ kr6,
                     const _Float16* __restrict__ v4,
                     const unsigned int* __restrict__ mp,
                     float* __restrict__ out,
                     float* __restrict__ score) {
    __shared__ unsigned int maskb[16 * 64];       // 4 KB
    __shared__ float        sums8[8][16];         // 512 B, per-wave slots
    __shared__ float        outb[8 * 16 * 64];    // 32 KB, per-wave slices

    // XCD-aware bijective swizzle: 4096 WGs -> contiguous 512 per XCD
    int wgid = (blockIdx.x & 7) * 512 + (blockIdx.x >> 3);
    int qt = wgid & 127;
    int bh = wgid >> 7;
    int b  = bh >> 4;
    int q0 = qt * 16;

    int tid = threadIdx.x;
    int w   = tid >> 6;
    int l   = tid & 63;
    int lm  = l & 15;
    int lp  = l >> 4;

    {
        const unsigned int* mrow = mp + ((size_t)b * NS + q0) * 64;
        for (int i = tid; i < 16 * 64; i += TPB) maskb[i] = mrow[i];
    }

    // Q B-fragment (col n = q = lm, k-slice d = lp*8+[0..7] (+32))
    const _Float16* qrow = qr + ((size_t)bh * NS + q0 + lm) * ND;
    half8 a0 = *(const half8*)(qrow + lp * 8);
    half8 a1 = *(const half8*)(qrow + 32 + lp * 8);
    // kr6 base for this bh; wave w covers key-tiles [w*16, w*16+16)
    const _Float16* k6 = kr6 + (size_t)bh * 128 * 1024;
    wg_barrier_lds();                      // maskb visible

    // ---- phase 1: S^T = K·Q^T -> masked exp -> packed regs + lane row-sum ----
    half4 earr[16];
    float ps = 0.0f;
#pragma unroll
    for (int t = 0; t < 16; ++t) {
        int kt = w * 16 + t;
        const _Float16* kp = k6 + (size_t)kt * 1024 + l * 8;
        half8 b0 = *(const half8*)(kp);          // 1024B contiguous wave-load
        half8 b1 = *(const half8*)(kp + 512);
        float4v acc = {0.f, 0.f, 0.f, 0.f};
        acc = __builtin_amdgcn_mfma_f32_16x16x32_f16(b0, a0, acc, 0, 0, 0);  // A=K rows
        acc = __builtin_amdgcn_mfma_f32_16x16x32_f16(b1, a1, acc, 0, 0, 0);  // B=Q rows
        // acc[r]: key = kt*16 + lp*4 + r, q = q0 + lm
        int keyb = kt * 16 + lp * 4;
        unsigned int mw = maskb[lm * 64 + (keyb >> 5)];
        int bit0 = keyb & 31;
        half4 ep;
#pragma unroll
        for (int r = 0; r < 4; ++r) {
            float ev = ((mw >> (bit0 + r)) & 1u) ? __expf(acc[r] * 0.125f) : 0.0f;
            ps += ev;
            ep[r] = (_Float16)ev;
        }
        earr[t] = ep;
    }
    ps += __shfl_xor(ps, 16);
    ps += __shfl_xor(ps, 32);
    if (lp == 0) sums8[w][lm] = ps;        // plain store, unique slot
    wg_barrier_lds();                       // sums8 visible (stores NOT drained)

    // ---- phase 2: interleaved {score nt-store | PV MFMA} per key-subtile ----
    {
        float s = 0.0f;
#pragma unroll
        for (int ww = 0; ww < 8; ++ww) s += sums8[ww][lm];   // fixed order
        float iv = (s > 0.0f) ? (1.0f / s) : 0.0f;
        float* srow = score + ((size_t)bh * NS + q0 + lm) * NS + w * 256 + lp * 4;

        float4v ac0 = {0.f, 0.f, 0.f, 0.f};
        float4v ac1 = {0.f, 0.f, 0.f, 0.f};
        float4v ac2 = {0.f, 0.f, 0.f, 0.f};
        float4v ac3 = {0.f, 0.f, 0.f, 0.f};
        const _Float16* vb = v4 + (size_t)bh * 128 * 1024 + l * 4;
#pragma unroll
        for (int st = 0; st < 16; ++st) {
            // score store for this key-subtile (nt: bypass L2, keep kr6/v4 resident)
            half4 e = earr[st];
            float4v f;
            f[0] = (float)e[0] * iv;
            f[1] = (float)e[1] * iv;
            f[2] = (float)e[2] * iv;
            f[3] = (float)e[3] * iv;
            __builtin_nontemporal_store(f, (float4v*)(srow + st * 16));

            // PV for this key-subtile
            int kt = w * 16 + st;
            const _Float16* vp = vb + (size_t)kt * 1024;
            half4 af0 = *(const half4*)(vp);         // 512B contiguous wave-loads
            half4 af1 = *(const half4*)(vp + 256);
            half4 af2 = *(const half4*)(vp + 512);
            half4 af3 = *(const half4*)(vp + 768);
            __builtin_amdgcn_s_setprio(1);
            ac0 = __builtin_amdgcn_mfma_f32_16x16x16f16(af0, e, ac0, 0, 0, 0);
            ac1 = __builtin_amdgcn_mfma_f32_16x16x16f16(af1, e, ac1, 0, 0, 0);
            ac2 = __builtin_amdgcn_mfma_f32_16x16x16f16(af2, e, ac2, 0, 0, 0);
            ac3 = __builtin_amdgcn_mfma_f32_16x16x16f16(af3, e, ac3, 0, 0, 0);
            __builtin_amdgcn_s_setprio(0);
        }
        // C-frag: q = lm (cols), d_local = lp*4 + reg; per-wave slice, plain stores
        float* ow = outb + w * 1024 + lm * 64 + lp * 4;
#pragma unroll
        for (int r = 0; r < 4; ++r) {
            ow[ 0 + r] = ac0[r];
            ow[16 + r] = ac1[r];
            ow[32 + r] = ac2[r];
            ow[48 + r] = ac3[r];
        }
    }
    wg_barrier_lds();   // outb visible (score stores still in flight)

    // ---- phase 3: out = (sum of 8 wave slices) * invs (nt) ----
    {
        float* orow = out + ((size_t)bh * NS + q0) * ND;
        for (int i = tid; i < 16 * 64; i += TPB) {
            int r = i >> 6;
            float s = 0.0f;
#pragma unroll
            for (int ww = 0; ww < 8; ++ww) s += sums8[ww][r];  // fixed order
            float iv = (s > 0.0f) ? (1.0f / s) : 0.0f;
            float acc = 0.0f;
#pragma unroll
            for (int ww = 0; ww < 8; ++ww) acc += outb[ww * 1024 + i];
            __builtin_nontemporal_store(acc * iv, &orow[i]);
        }
    }
}

// ---------------------------------------------------------------------------
extern "C" void kernel_launch(void* const* d_in, const int* in_sizes, int n_in,
                              void* d_out, int out_size, void* d_ws, size_t ws_size,
                              hipStream_t stream) {
    const float* q    = (const float*)d_in[0];
    const float* k    = (const float*)d_in[1];
    const float* v    = (const float*)d_in[2];
    const int*   mask = (const int*)d_in[3];

    float* out   = (float*)d_out;            // [B,H,S,D]
    float* score = out + (size_t)NE;         // [B,H,S,S]

    _Float16* qrw = (_Float16*)d_ws;
    _Float16* kr6 = qrw + NE;
    _Float16* v4w = kr6 + NE;
    unsigned int* mp = (unsigned int*)(v4w + NE);   // NB*NS*NS/32 words = 1 MB

    prep_kernel<<<dim3(ROPE_BLKS + VT_BLKS + MP_BLKS), dim3(256), 0, stream>>>(
        q, k, v, mask, qrw, kr6, v4w, mp);
    attn_reg_kernel<<<dim3(NB * NH * (NS / 16)), dim3(TPB), 0, stream>>>(
        qrw, kr6, v4w, mp, out, score);
}